// Round 6
// baseline (328.500 us; speedup 1.0000x reference)
//
#include <hip/hip_runtime.h>
#include <math.h>

#define B_ROWS 32768
#define K_CODES 4096
#define D_DIM 128
#define MARGIN 1.5e-3f
#define CAP 32

typedef short bf16x8 __attribute__((ext_vector_type(8)));
typedef float f32x4 __attribute__((ext_vector_type(4)));

// RNE float->bf16 (finite inputs only)
__device__ __forceinline__ unsigned short f2bf(float f) {
  union { float f; unsigned int u; } v; v.f = f;
  unsigned int r = (v.u + 0x7FFFu + ((v.u >> 16) & 1u)) >> 16;
  return (unsigned short)r;
}

// ---------------------------------------------------------------------------
// Kernel 1: prep — x2/e2 (numpy pairwise order, validated) + eb bf16 cast in
// MFMA-FRAGMENT order: eb[tile][ks][lane] (lane=q*16+lr), so each B-fragment
// load in vq_main is one fully-coalesced 1KB wave load.
//   og = tile*256 + ks*64 + q*16 + lr  maps to  emb row tile*16+lr,
//   cols ks*32+q*8 .. +7.   (Pure permutation of the same bf16 values.)
// ---------------------------------------------------------------------------
__global__ __launch_bounds__(256) void prep(const float* __restrict__ x,
                                            const float* __restrict__ emb,
                                            float* __restrict__ x2,
                                            float* __restrict__ e2,
                                            unsigned short* __restrict__ ebb) {
  const int t0 = blockIdx.x * 256 + threadIdx.x;
  const int stride = gridDim.x * 256;
  // (a) x2: 8 lanes/row, validated pairwise order
  for (int s = t0; s < B_ROWS * 8; s += stride) {
    int row = s >> 3, lane = s & 7;
    const float* src = x + (size_t)row * D_DIM;
    float v = src[lane];
    float t = v * v;
    asm volatile("" : "+v"(t));
    float acc = t;
#pragma unroll
    for (int i = 1; i < 16; ++i) {
      float w = src[i * 8 + lane];
      float tt = w * w;
      asm volatile("" : "+v"(tt));
      acc = acc + tt;
    }
    acc = acc + __shfl_xor(acc, 1, 64);
    acc = acc + __shfl_xor(acc, 2, 64);
    acc = acc + __shfl_xor(acc, 4, 64);
    if (lane == 0) x2[row] = acc;
  }
  // (b) e2, same recipe
  for (int s = t0; s < K_CODES * 8; s += stride) {
    int row = s >> 3, lane = s & 7;
    const float* src = emb + (size_t)row * D_DIM;
    float v = src[lane];
    float t = v * v;
    asm volatile("" : "+v"(t));
    float acc = t;
#pragma unroll
    for (int i = 1; i < 16; ++i) {
      float w = src[i * 8 + lane];
      float tt = w * w;
      asm volatile("" : "+v"(tt));
      acc = acc + tt;
    }
    acc = acc + __shfl_xor(acc, 1, 64);
    acc = acc + __shfl_xor(acc, 2, 64);
    acc = acc + __shfl_xor(acc, 4, 64);
    if (lane == 0) e2[row] = acc;
  }
  // (c) emb -> bf16 cast into fragment order
  for (int og = t0; og < K_CODES * D_DIM / 8; og += stride) {
    int tile = og >> 8, ks = (og >> 6) & 3, qq = (og >> 4) & 3, lr2 = og & 15;
    const float* src = emb + (size_t)(tile * 16 + lr2) * D_DIM + ks * 32 + qq * 8;
    float4 a = *(const float4*)src;
    float4 b = *(const float4*)(src + 4);
    ushort4 o0 = make_ushort4(f2bf(a.x), f2bf(a.y), f2bf(a.z), f2bf(a.w));
    ushort4 o1 = make_ushort4(f2bf(b.x), f2bf(b.y), f2bf(b.z), f2bf(b.w));
    ((ushort4*)ebb)[og * 2] = o0;
    ((ushort4*)ebb)[og * 2 + 1] = o1;
  }
}

// ---------------------------------------------------------------------------
// Kernel 2: fused two-phase MFMA argmin + exact rescore + gather/losses.
// r4 (64-row) validated structure; ONLY change: explicit named register
// double-buffer (bA/bB) for the B-fragments in both passes — loads for chunk
// ch+1 are issued BEFORE the MFMA block of chunk ch, so the waitcnt in front
// of each MFMA block covers loads issued a full compute block earlier
// (distance-1 software pipeline; r5 showed TLP alone can't hide the L2
// latency of loads feeding the immediately-next MFMAs).
// launch_bounds (256,2): r3 proved tighter bounds spill the accumulators.
// ---------------------------------------------------------------------------
__global__ __launch_bounds__(256, 2) void vq_main(
    const float* __restrict__ x, const float* __restrict__ emb,
    const unsigned short* __restrict__ eb,
    const float* __restrict__ x2g, const float* __restrict__ e2g,
    float* __restrict__ out_q, float* __restrict__ out_idx,
    unsigned int* __restrict__ counts, double* __restrict__ sums) {
  __shared__ float smem[9680];
  float* m2 = smem;                                   // [64][4] overlay xf (dead pre-xf)
  float* xf = smem;                                   // [64][132] fp32 (staged post-loop)
  unsigned short* lists = (unsigned short*)(smem + 8448);  // [64][CAP] u16
  float* redv = smem + 8448;                          // overlay lists (fallback)
  int* redi = (int*)(smem + 8704);                    // overlay lists (fallback)
  float* mlims = smem + 9472;                         // [64]
  unsigned int* cnt = (unsigned int*)(smem + 9536);   // [64]
  int* bidxs = (int*)(smem + 9600);                   // [64]
  double* lred = (double*)(smem + 9664);              // [8]

  const int tid = threadIdx.x;
  const int wid = tid >> 6;        // 0..3 -> n-tiles wid*2, wid*2+1
  const int lane = tid & 63;
  const int q = lane >> 4, lr = lane & 15;
  const int rowbase = blockIdx.x * 64;
  const bf16x8* ebv = (const bf16x8*)eb;

  // hoist A fragments: af[mi][ks] = bf16(x[rowbase+mi*16+lr][ks*32+q*8 ..+7])
  bf16x8 af[4][4];
#pragma unroll
  for (int mi = 0; mi < 4; ++mi) {
    const float* xr = x + (size_t)(rowbase + mi * 16 + lr) * D_DIM;
#pragma unroll
    for (int ks = 0; ks < 4; ++ks) {
      float4 v0 = *(const float4*)(xr + ks * 32 + q * 8);
      float4 v1 = *(const float4*)(xr + ks * 32 + q * 8 + 4);
      bf16x8 f;
      f[0] = (short)f2bf(v0.x); f[1] = (short)f2bf(v0.y);
      f[2] = (short)f2bf(v0.z); f[3] = (short)f2bf(v0.w);
      f[4] = (short)f2bf(v1.x); f[5] = (short)f2bf(v1.y);
      f[6] = (short)f2bf(v1.z); f[7] = (short)f2bf(v1.w);
      af[mi][ks] = f;
    }
  }

  // ---------------- pass A: global min of t~ per row ----------------
  float rm[4][4];
#pragma unroll
  for (int mi = 0; mi < 4; ++mi)
#pragma unroll
    for (int rg = 0; rg < 4; ++rg) rm[mi][rg] = 3.4e38f;

  {
    bf16x8 bA[2][4], bB[2][4];
    // prologue: chunk 0 -> bA
#pragma unroll
    for (int ni = 0; ni < 2; ++ni) {
      const bf16x8* tb = ebv + ((size_t)(wid * 2 + ni) * 256 + lane);
#pragma unroll
      for (int ks = 0; ks < 4; ++ks) bA[ni][ks] = tb[ks * 64];
    }
    for (int ch2 = 0; ch2 < 32; ch2 += 2) {
      // prefetch ch2+1 -> bB
#pragma unroll
      for (int ni = 0; ni < 2; ++ni) {
        const bf16x8* tb =
            ebv + ((size_t)((ch2 + 1) * 8 + wid * 2 + ni) * 256 + lane);
#pragma unroll
        for (int ks = 0; ks < 4; ++ks) bB[ni][ks] = tb[ks * 64];
      }
      // compute bA @ ch2
      {
        f32x4 acc[4][2];
#pragma unroll
        for (int mi = 0; mi < 4; ++mi)
#pragma unroll
          for (int ni = 0; ni < 2; ++ni) {
            f32x4 z = {0.f, 0.f, 0.f, 0.f};
            acc[mi][ni] = z;
          }
#pragma unroll
        for (int ks = 0; ks < 4; ++ks)
#pragma unroll
          for (int mi = 0; mi < 4; ++mi)
#pragma unroll
            for (int ni = 0; ni < 2; ++ni)
              acc[mi][ni] = __builtin_amdgcn_mfma_f32_16x16x32_bf16(
                  af[mi][ks], bA[ni][ks], acc[mi][ni], 0, 0, 0);
#pragma unroll
        for (int ni = 0; ni < 2; ++ni) {
          float ev = e2g[ch2 * 128 + (wid * 2 + ni) * 16 + lr];
#pragma unroll
          for (int mi = 0; mi < 4; ++mi)
#pragma unroll
            for (int rg = 0; rg < 4; ++rg) {
              float t = __builtin_fmaf(-2.0f, acc[mi][ni][rg], ev);
              rm[mi][rg] = fminf(rm[mi][rg], t);
            }
        }
      }
      // prefetch ch2+2 -> bA (wraps to 0 on last iter; dead loads, harmless)
      {
        int chn = (ch2 + 2) & 31;
#pragma unroll
        for (int ni = 0; ni < 2; ++ni) {
          const bf16x8* tb =
              ebv + ((size_t)(chn * 8 + wid * 2 + ni) * 256 + lane);
#pragma unroll
          for (int ks = 0; ks < 4; ++ks) bA[ni][ks] = tb[ks * 64];
        }
      }
      // compute bB @ ch2+1
      {
        f32x4 acc[4][2];
#pragma unroll
        for (int mi = 0; mi < 4; ++mi)
#pragma unroll
          for (int ni = 0; ni < 2; ++ni) {
            f32x4 z = {0.f, 0.f, 0.f, 0.f};
            acc[mi][ni] = z;
          }
#pragma unroll
        for (int ks = 0; ks < 4; ++ks)
#pragma unroll
          for (int mi = 0; mi < 4; ++mi)
#pragma unroll
            for (int ni = 0; ni < 2; ++ni)
              acc[mi][ni] = __builtin_amdgcn_mfma_f32_16x16x32_bf16(
                  af[mi][ks], bB[ni][ks], acc[mi][ni], 0, 0, 0);
#pragma unroll
        for (int ni = 0; ni < 2; ++ni) {
          float ev = e2g[(ch2 + 1) * 128 + (wid * 2 + ni) * 16 + lr];
#pragma unroll
          for (int mi = 0; mi < 4; ++mi)
#pragma unroll
            for (int rg = 0; rg < 4; ++rg) {
              float t = __builtin_fmaf(-2.0f, acc[mi][ni][rg], ev);
              rm[mi][rg] = fminf(rm[mi][rg], t);
            }
        }
      }
    }
  }

  // reduce min across the 16 col-lanes, then across the 4 waves
#pragma unroll
  for (int mi = 0; mi < 4; ++mi)
#pragma unroll
    for (int rg = 0; rg < 4; ++rg) {
      float v = rm[mi][rg];
      v = fminf(v, __shfl_xor(v, 1, 64));
      v = fminf(v, __shfl_xor(v, 2, 64));
      v = fminf(v, __shfl_xor(v, 4, 64));
      v = fminf(v, __shfl_xor(v, 8, 64));
      if (lr == 0) m2[(mi * 16 + q * 4 + rg) * 4 + wid] = v;
    }
  __syncthreads();
  if (tid < 64) {
    float a = fminf(m2[tid * 4], m2[tid * 4 + 1]);
    float b = fminf(m2[tid * 4 + 2], m2[tid * 4 + 3]);
    mlims[tid] = fminf(a, b) + MARGIN;
    cnt[tid] = 0;
  }
  __syncthreads();

  // ---------------- pass B: collect candidates ----------------
  float ml[4][4];
#pragma unroll
  for (int mi = 0; mi < 4; ++mi)
#pragma unroll
    for (int rg = 0; rg < 4; ++rg) ml[mi][rg] = mlims[mi * 16 + q * 4 + rg];

  {
    bf16x8 bA[2][4], bB[2][4];
#pragma unroll
    for (int ni = 0; ni < 2; ++ni) {
      const bf16x8* tb = ebv + ((size_t)(wid * 2 + ni) * 256 + lane);
#pragma unroll
      for (int ks = 0; ks < 4; ++ks) bA[ni][ks] = tb[ks * 64];
    }
    for (int ch2 = 0; ch2 < 32; ch2 += 2) {
      // prefetch ch2+1 -> bB
#pragma unroll
      for (int ni = 0; ni < 2; ++ni) {
        const bf16x8* tb =
            ebv + ((size_t)((ch2 + 1) * 8 + wid * 2 + ni) * 256 + lane);
#pragma unroll
        for (int ks = 0; ks < 4; ++ks) bB[ni][ks] = tb[ks * 64];
      }
      // compute bA @ ch2
      {
        f32x4 acc[4][2];
#pragma unroll
        for (int mi = 0; mi < 4; ++mi)
#pragma unroll
          for (int ni = 0; ni < 2; ++ni) {
            f32x4 z = {0.f, 0.f, 0.f, 0.f};
            acc[mi][ni] = z;
          }
#pragma unroll
        for (int ks = 0; ks < 4; ++ks)
#pragma unroll
          for (int mi = 0; mi < 4; ++mi)
#pragma unroll
            for (int ni = 0; ni < 2; ++ni)
              acc[mi][ni] = __builtin_amdgcn_mfma_f32_16x16x32_bf16(
                  af[mi][ks], bA[ni][ks], acc[mi][ni], 0, 0, 0);
#pragma unroll
        for (int ni = 0; ni < 2; ++ni) {
          int colbase = ch2 * 128 + (wid * 2 + ni) * 16 + lr;
          float ev = e2g[colbase];
#pragma unroll
          for (int mi = 0; mi < 4; ++mi)
#pragma unroll
            for (int rg = 0; rg < 4; ++rg) {
              float t = __builtin_fmaf(-2.0f, acc[mi][ni][rg], ev);
              if (t <= ml[mi][rg]) {
                int row = mi * 16 + q * 4 + rg;
                unsigned int p = atomicAdd(&cnt[row], 1u);
                if (p < CAP) lists[row * CAP + p] = (unsigned short)colbase;
              }
            }
        }
      }
      // prefetch ch2+2 -> bA (wrap; dead on last iter)
      {
        int chn = (ch2 + 2) & 31;
#pragma unroll
        for (int ni = 0; ni < 2; ++ni) {
          const bf16x8* tb =
              ebv + ((size_t)(chn * 8 + wid * 2 + ni) * 256 + lane);
#pragma unroll
          for (int ks = 0; ks < 4; ++ks) bA[ni][ks] = tb[ks * 64];
        }
      }
      // compute bB @ ch2+1
      {
        f32x4 acc[4][2];
#pragma unroll
        for (int mi = 0; mi < 4; ++mi)
#pragma unroll
          for (int ni = 0; ni < 2; ++ni) {
            f32x4 z = {0.f, 0.f, 0.f, 0.f};
            acc[mi][ni] = z;
          }
#pragma unroll
        for (int ks = 0; ks < 4; ++ks)
#pragma unroll
          for (int mi = 0; mi < 4; ++mi)
#pragma unroll
            for (int ni = 0; ni < 2; ++ni)
              acc[mi][ni] = __builtin_amdgcn_mfma_f32_16x16x32_bf16(
                  af[mi][ks], bB[ni][ks], acc[mi][ni], 0, 0, 0);
#pragma unroll
        for (int ni = 0; ni < 2; ++ni) {
          int colbase = (ch2 + 1) * 128 + (wid * 2 + ni) * 16 + lr;
          float ev = e2g[colbase];
#pragma unroll
          for (int mi = 0; mi < 4; ++mi)
#pragma unroll
            for (int rg = 0; rg < 4; ++rg) {
              float t = __builtin_fmaf(-2.0f, acc[mi][ni][rg], ev);
              if (t <= ml[mi][rg]) {
                int row = mi * 16 + q * 4 + rg;
                unsigned int p = atomicAdd(&cnt[row], 1u);
                if (p < CAP) lists[row * CAP + p] = (unsigned short)colbase;
              }
            }
        }
      }
    }
  }

  // ---------------- phase 2: stage fp32 x rows, exact rescore ----------------
  __syncthreads();  // lists/cnt final; m2 dead -> xf may be written
  {
    const float4* src = (const float4*)(x + (size_t)rowbase * D_DIM);
#pragma unroll
    for (int p = 0; p < 8; ++p) {
      int idx = p * 256 + tid;            // float4 index over 64x128
      int r = idx >> 5, c = idx & 31;     // row, float4-col
      *(float4*)(xf + r * 132 + c * 4) = src[idx];
    }
  }
  __syncthreads();

  if (tid < 64 && cnt[tid] <= CAP) {
    int c = (int)cnt[tid];
    float xs2 = x2g[rowbase + tid];
    float best = 3.4e38f;
    int bidx = 0x7fffffff;
    const float* xr = xf + tid * 132;
    for (int j = 0; j < c; ++j) {
      int col = lists[tid * CAP + j];
      float dot = 0.f;
      const float4* ev = (const float4*)(emb + (size_t)col * D_DIM);
#pragma unroll 8
      for (int d4 = 0; d4 < 32; ++d4) {  // exact ascending-d fmaf chain
        float4 e4 = ev[d4];
        dot = __builtin_fmaf(xr[d4 * 4 + 0], e4.x, dot);
        dot = __builtin_fmaf(xr[d4 * 4 + 1], e4.y, dot);
        dot = __builtin_fmaf(xr[d4 * 4 + 2], e4.z, dot);
        dot = __builtin_fmaf(xr[d4 * 4 + 3], e4.w, dot);
      }
      float t1 = xs2 + e2g[col];                 // fl(x2+e2)
      float s = __builtin_fmaf(-2.0f, dot, t1);  // fl(t1 - 2*dot)
      if (s < best || (s == best && col < bidx)) { best = s; bidx = col; }
    }
    out_idx[rowbase + tid] = (float)bidx;
    bidxs[tid] = bidx;
    atomicAdd(&counts[bidx], 1u);
  }
  __syncthreads();

  // overflow fallback: exact full scan (expected never); cnt[r] block-uniform
  for (int r = 0; r < 64; ++r) {
    if (cnt[r] <= CAP) continue;
    float xs2 = x2g[rowbase + r];
    const float* xr = xf + r * 132;
    float lbest = 3.4e38f;
    int lidx = 0x7fffffff;
    for (int c0 = tid; c0 < K_CODES; c0 += 256) {
      float dot = 0.f;
      const float4* ev = (const float4*)(emb + (size_t)c0 * D_DIM);
      for (int d4 = 0; d4 < 32; ++d4) {
        float4 e4 = ev[d4];
        dot = __builtin_fmaf(xr[d4 * 4 + 0], e4.x, dot);
        dot = __builtin_fmaf(xr[d4 * 4 + 1], e4.y, dot);
        dot = __builtin_fmaf(xr[d4 * 4 + 2], e4.z, dot);
        dot = __builtin_fmaf(xr[d4 * 4 + 3], e4.w, dot);
      }
      float s = __builtin_fmaf(-2.0f, dot, xs2 + e2g[c0]);
      if (s < lbest || (s == lbest && c0 < lidx)) { lbest = s; lidx = c0; }
    }
    redv[tid] = lbest;
    redi[tid] = lidx;
    __syncthreads();
    if (tid == 0) {
      float bv = redv[0]; int bi = redi[0];
      for (int t = 1; t < 256; ++t) {
        float v = redv[t]; int i2 = redi[t];
        if (v < bv || (v == bv && i2 < bi)) { bv = v; bi = i2; }
      }
      out_idx[rowbase + r] = (float)bi;
      bidxs[r] = bi;
      atomicAdd(&counts[bi], 1u);
    }
    __syncthreads();
  }
  __syncthreads();  // bidxs ready for all rows

  // ---------------- fused gather + straight-through + losses ----------------
  // st = fl(x + fl(q-x)); e-term fl((q-x)^2), q-term fl((st-x)^2); dbl accum.
  {
    int gr = tid >> 2, seg = tid & 3;
    int gidx = bidxs[gr];
    const float4* ev = (const float4*)(emb + (size_t)gidx * D_DIM + seg * 32);
    const float* xvp = xf + gr * 132 + seg * 32;
    float4* oq = (float4*)(out_q + (size_t)(rowbase + gr) * D_DIM + seg * 32);
    double es = 0.0, qs = 0.0;
#pragma unroll
    for (int j = 0; j < 8; ++j) {
      float4 e4 = ev[j];
      float4 xv = *(const float4*)(xvp + j * 4);
      float d0 = e4.x - xv.x, d1 = e4.y - xv.y, d2 = e4.z - xv.z, d3 = e4.w - xv.w;
      float s0 = xv.x + d0, s1 = xv.y + d1, s2 = xv.z + d2, s3 = xv.w + d3;
      oq[j] = make_float4(s0, s1, s2, s3);
      float g0 = s0 - xv.x, g1 = s1 - xv.y, g2 = s2 - xv.z, g3 = s3 - xv.w;
      es += (double)(d0 * d0) + (double)(d1 * d1) + (double)(d2 * d2) + (double)(d3 * d3);
      qs += (double)(g0 * g0) + (double)(g1 * g1) + (double)(g2 * g2) + (double)(g3 * g3);
    }
#pragma unroll
    for (int off = 32; off >= 1; off >>= 1) {
      es += __shfl_down(es, off, 64);
      qs += __shfl_down(qs, off, 64);
    }
    if (lane == 0) { lred[wid * 2] = es; lred[wid * 2 + 1] = qs; }
    __syncthreads();
    if (tid == 0) {
      double e = lred[0] + lred[2] + lred[4] + lred[6];
      double qq = lred[1] + lred[3] + lred[5] + lred[7];
      atomicAdd(&sums[0], e);
      atomicAdd(&sums[1], qq);
    }
  }
}

// ---------------------------------------------------------------------------
// Kernel 3 (validated): finalize scalars.
// ---------------------------------------------------------------------------
__global__ __launch_bounds__(256) void vq_final(const unsigned int* __restrict__ counts,
                                                const double* __restrict__ sums,
                                                float* __restrict__ out_scalars) {
  double s = 0.0;
  for (int k = threadIdx.x; k < K_CODES; k += 256) {
    float p = (float)counts[k] * (1.0f / 32768.0f);
    float term = p * logf(p + 1e-10f);
    s += (double)term;
  }
#pragma unroll
  for (int off = 32; off >= 1; off >>= 1) s += __shfl_down(s, off, 64);
  __shared__ double red[4];
  if ((threadIdx.x & 63) == 0) red[threadIdx.x >> 6] = s;
  __syncthreads();
  if (threadIdx.x == 0) {
    double tot = red[0] + red[1] + red[2] + red[3];
    float e_lat = (float)(sums[0] / (double)(B_ROWS * D_DIM));
    float q_lat = (float)(sums[1] / (double)(B_ROWS * D_DIM));
    float vq = q_lat + 0.25f * e_lat;   // fl(q + fl(0.25*e)); 0.25*e exact
    out_scalars[0] = vq;
    out_scalars[1] = e_lat;
    out_scalars[2] = q_lat;
    out_scalars[3] = expf(-(float)tot);
  }
}

extern "C" void kernel_launch(void* const* d_in, const int* in_sizes, int n_in,
                              void* d_out, int out_size, void* d_ws, size_t ws_size,
                              hipStream_t stream) {
  const float* x = (const float*)d_in[0];
  const float* emb = (const float*)d_in[1];
  float* out = (float*)d_out;

  // ws: counts[4096]u32 @0 | sums[2]f64 @16384 | x2[32768] @16400 |
  //     e2[4096] @147472 | eb[4096*128]u16 @163856   (~1.21 MB total)
  unsigned int* counts = (unsigned int*)d_ws;
  double* sums = (double*)((char*)d_ws + 16384);
  float* x2 = (float*)((char*)d_ws + 16400);
  float* e2 = (float*)((char*)d_ws + 147472);
  unsigned short* eb = (unsigned short*)((char*)d_ws + 163856);

  float* out_idx = out + (size_t)B_ROWS * D_DIM;
  float* out_scalars = out_idx + B_ROWS;

  hipMemsetAsync(d_ws, 0, 16400, stream);  // zero counts + sums
  prep<<<512, 256, 0, stream>>>(x, emb, x2, e2, eb);
  vq_main<<<B_ROWS / 64, 256, 0, stream>>>(x, emb, eb, x2, e2, out, out_idx,
                                           counts, sums);
  vq_final<<<1, 256, 0, stream>>>(counts, sums, out_scalars);
}

// Round 7
// 282.826 us; speedup vs baseline: 1.1615x; 1.1615x over previous
//
#include <hip/hip_runtime.h>
#include <math.h>

#define B_ROWS 32768
#define K_CODES 4096
#define D_DIM 128
#define MARGIN 1.5e-3f
#define CAP 32

typedef short bf16x8 __attribute__((ext_vector_type(8)));
typedef float f32x4 __attribute__((ext_vector_type(4)));

// RNE float->bf16 (finite inputs only)
__device__ __forceinline__ unsigned short f2bf(float f) {
  union { float f; unsigned int u; } v; v.f = f;
  unsigned int r = (v.u + 0x7FFFu + ((v.u >> 16) & 1u)) >> 16;
  return (unsigned short)r;
}

// ---------------------------------------------------------------------------
// Kernel 1: prep — x2/e2 (numpy pairwise order, validated) + eb bf16 cast in
// MFMA-FRAGMENT order (validated r4): og = tile*256 + ks*64 + q*16 + lr maps
// to emb row tile*16+lr, cols ks*32+q*8 .. +7.
// ---------------------------------------------------------------------------
__global__ __launch_bounds__(256) void prep(const float* __restrict__ x,
                                            const float* __restrict__ emb,
                                            float* __restrict__ x2,
                                            float* __restrict__ e2,
                                            unsigned short* __restrict__ ebb) {
  const int t0 = blockIdx.x * 256 + threadIdx.x;
  const int stride = gridDim.x * 256;
  for (int s = t0; s < B_ROWS * 8; s += stride) {
    int row = s >> 3, lane = s & 7;
    const float* src = x + (size_t)row * D_DIM;
    float v = src[lane];
    float t = v * v;
    asm volatile("" : "+v"(t));
    float acc = t;
#pragma unroll
    for (int i = 1; i < 16; ++i) {
      float w = src[i * 8 + lane];
      float tt = w * w;
      asm volatile("" : "+v"(tt));
      acc = acc + tt;
    }
    acc = acc + __shfl_xor(acc, 1, 64);
    acc = acc + __shfl_xor(acc, 2, 64);
    acc = acc + __shfl_xor(acc, 4, 64);
    if (lane == 0) x2[row] = acc;
  }
  for (int s = t0; s < K_CODES * 8; s += stride) {
    int row = s >> 3, lane = s & 7;
    const float* src = emb + (size_t)row * D_DIM;
    float v = src[lane];
    float t = v * v;
    asm volatile("" : "+v"(t));
    float acc = t;
#pragma unroll
    for (int i = 1; i < 16; ++i) {
      float w = src[i * 8 + lane];
      float tt = w * w;
      asm volatile("" : "+v"(tt));
      acc = acc + tt;
    }
    acc = acc + __shfl_xor(acc, 1, 64);
    acc = acc + __shfl_xor(acc, 2, 64);
    acc = acc + __shfl_xor(acc, 4, 64);
    if (lane == 0) e2[row] = acc;
  }
  for (int og = t0; og < K_CODES * D_DIM / 8; og += stride) {
    int tile = og >> 8, ks = (og >> 6) & 3, qq = (og >> 4) & 3, lr2 = og & 15;
    const float* src = emb + (size_t)(tile * 16 + lr2) * D_DIM + ks * 32 + qq * 8;
    float4 a = *(const float4*)src;
    float4 b = *(const float4*)(src + 4);
    ushort4 o0 = make_ushort4(f2bf(a.x), f2bf(a.y), f2bf(a.z), f2bf(a.w));
    ushort4 o1 = make_ushort4(f2bf(b.x), f2bf(b.y), f2bf(b.z), f2bf(b.w));
    ((ushort4*)ebb)[og * 2] = o0;
    ((ushort4*)ebb)[og * 2 + 1] = o1;
  }
}

// ---------------------------------------------------------------------------
// Kernel 2a: vq_scan — passes A+B only (r5 loop bodies verbatim), 32 rows per
// block, 1024 blocks.  LDS shrunk to 2.8KB (no xf/tail buffers) so residency
// is VGPR-limited (~84 regs -> 4-6 blocks/CU).  lists/cnt written to ws.
// This split is also the phase-level measurement: rocprof now reports scan
// and tail durations separately.
// ---------------------------------------------------------------------------
__global__ __launch_bounds__(256, 2) void vq_scan(
    const float* __restrict__ x, const unsigned short* __restrict__ eb,
    const float* __restrict__ e2g,
    unsigned short* __restrict__ lists_g, unsigned int* __restrict__ cnt_g) {
  __shared__ float smem[704];  // 2816B
  unsigned short* lists = (unsigned short*)smem;      // [32][CAP] u16 = 2048B
  float* m2 = smem + 512;                             // [32][4]
  float* mlims = smem + 640;                          // [32]
  unsigned int* cnt = (unsigned int*)(smem + 672);    // [32]

  const int tid = threadIdx.x;
  const int wid = tid >> 6;
  const int lane = tid & 63;
  const int q = lane >> 4, lr = lane & 15;
  const int rowbase = blockIdx.x * 32;
  const bf16x8* ebv = (const bf16x8*)eb;

  // hoist A fragments
  bf16x8 af[2][4];
#pragma unroll
  for (int mi = 0; mi < 2; ++mi) {
    const float* xr = x + (size_t)(rowbase + mi * 16 + lr) * D_DIM;
#pragma unroll
    for (int ks = 0; ks < 4; ++ks) {
      float4 v0 = *(const float4*)(xr + ks * 32 + q * 8);
      float4 v1 = *(const float4*)(xr + ks * 32 + q * 8 + 4);
      bf16x8 f;
      f[0] = (short)f2bf(v0.x); f[1] = (short)f2bf(v0.y);
      f[2] = (short)f2bf(v0.z); f[3] = (short)f2bf(v0.w);
      f[4] = (short)f2bf(v1.x); f[5] = (short)f2bf(v1.y);
      f[6] = (short)f2bf(v1.z); f[7] = (short)f2bf(v1.w);
      af[mi][ks] = f;
    }
  }

  // ---------------- pass A: global min of t~ per row ----------------
  float rm[2][4];
#pragma unroll
  for (int mi = 0; mi < 2; ++mi)
#pragma unroll
    for (int rg = 0; rg < 4; ++rg) rm[mi][rg] = 3.4e38f;

#pragma unroll 2
  for (int ch = 0; ch < 32; ++ch) {
    bf16x8 bf[2][4];
#pragma unroll
    for (int ni = 0; ni < 2; ++ni) {
      const bf16x8* tb = ebv + ((size_t)(ch * 8 + wid * 2 + ni) * 256 + lane);
#pragma unroll
      for (int ks = 0; ks < 4; ++ks) bf[ni][ks] = tb[ks * 64];
    }
    f32x4 acc[2][2];
#pragma unroll
    for (int mi = 0; mi < 2; ++mi)
#pragma unroll
      for (int ni = 0; ni < 2; ++ni) {
        f32x4 z = {0.f, 0.f, 0.f, 0.f};
        acc[mi][ni] = z;
      }
#pragma unroll
    for (int ks = 0; ks < 4; ++ks)
#pragma unroll
      for (int mi = 0; mi < 2; ++mi)
#pragma unroll
        for (int ni = 0; ni < 2; ++ni)
          acc[mi][ni] = __builtin_amdgcn_mfma_f32_16x16x32_bf16(
              af[mi][ks], bf[ni][ks], acc[mi][ni], 0, 0, 0);
#pragma unroll
    for (int ni = 0; ni < 2; ++ni) {
      float ev = e2g[ch * 128 + (wid * 2 + ni) * 16 + lr];
#pragma unroll
      for (int mi = 0; mi < 2; ++mi)
#pragma unroll
        for (int rg = 0; rg < 4; ++rg) {
          float t = __builtin_fmaf(-2.0f, acc[mi][ni][rg], ev);
          rm[mi][rg] = fminf(rm[mi][rg], t);
        }
    }
  }

  // reduce min across the 16 col-lanes, then across the 4 waves
#pragma unroll
  for (int mi = 0; mi < 2; ++mi)
#pragma unroll
    for (int rg = 0; rg < 4; ++rg) {
      float v = rm[mi][rg];
      v = fminf(v, __shfl_xor(v, 1, 64));
      v = fminf(v, __shfl_xor(v, 2, 64));
      v = fminf(v, __shfl_xor(v, 4, 64));
      v = fminf(v, __shfl_xor(v, 8, 64));
      if (lr == 0) m2[(mi * 16 + q * 4 + rg) * 4 + wid] = v;
    }
  __syncthreads();
  if (tid < 32) {
    float a = fminf(m2[tid * 4], m2[tid * 4 + 1]);
    float b = fminf(m2[tid * 4 + 2], m2[tid * 4 + 3]);
    mlims[tid] = fminf(a, b) + MARGIN;
    cnt[tid] = 0;
  }
  __syncthreads();

  // ---------------- pass B: collect candidates ----------------
  float ml[2][4];
#pragma unroll
  for (int mi = 0; mi < 2; ++mi)
#pragma unroll
    for (int rg = 0; rg < 4; ++rg) ml[mi][rg] = mlims[mi * 16 + q * 4 + rg];

#pragma unroll 2
  for (int ch = 0; ch < 32; ++ch) {
    bf16x8 bf[2][4];
#pragma unroll
    for (int ni = 0; ni < 2; ++ni) {
      const bf16x8* tb = ebv + ((size_t)(ch * 8 + wid * 2 + ni) * 256 + lane);
#pragma unroll
      for (int ks = 0; ks < 4; ++ks) bf[ni][ks] = tb[ks * 64];
    }
    f32x4 acc[2][2];
#pragma unroll
    for (int mi = 0; mi < 2; ++mi)
#pragma unroll
      for (int ni = 0; ni < 2; ++ni) {
        f32x4 z = {0.f, 0.f, 0.f, 0.f};
        acc[mi][ni] = z;
      }
#pragma unroll
    for (int ks = 0; ks < 4; ++ks)
#pragma unroll
      for (int mi = 0; mi < 2; ++mi)
#pragma unroll
        for (int ni = 0; ni < 2; ++ni)
          acc[mi][ni] = __builtin_amdgcn_mfma_f32_16x16x32_bf16(
              af[mi][ks], bf[ni][ks], acc[mi][ni], 0, 0, 0);
#pragma unroll
    for (int ni = 0; ni < 2; ++ni) {
      int colbase = ch * 128 + (wid * 2 + ni) * 16 + lr;
      float ev = e2g[colbase];
#pragma unroll
      for (int mi = 0; mi < 2; ++mi)
#pragma unroll
        for (int rg = 0; rg < 4; ++rg) {
          float t = __builtin_fmaf(-2.0f, acc[mi][ni][rg], ev);
          if (t <= ml[mi][rg]) {
            int row = mi * 16 + q * 4 + rg;
            unsigned int p = atomicAdd(&cnt[row], 1u);
            if (p < CAP) lists[row * CAP + p] = (unsigned short)colbase;
          }
        }
    }
  }

  // ---------------- write lists/cnt to workspace ----------------
  __syncthreads();
  // 32*CAP = 1024 u16 = 256 ushort4; one per thread
  ((ushort4*)(lists_g + (size_t)rowbase * CAP))[tid] = ((const ushort4*)lists)[tid];
  if (tid < 32) cnt_g[rowbase + tid] = cnt[tid];
}

// ---------------------------------------------------------------------------
// Kernel 2b: vq_tail — exact rescore + fallback + gather/losses (r5 verbatim
// numerics), reading lists/cnt from ws.  32 rows/block, 1024 blocks.
// ---------------------------------------------------------------------------
__global__ __launch_bounds__(256) void vq_tail(
    const float* __restrict__ x, const float* __restrict__ emb,
    const float* __restrict__ x2g, const float* __restrict__ e2g,
    const unsigned short* __restrict__ lists_g,
    const unsigned int* __restrict__ cnt_g,
    float* __restrict__ out_q, float* __restrict__ out_idx,
    unsigned int* __restrict__ counts, double* __restrict__ sums) {
  __shared__ float xf[32 * 132];       // 16896B
  __shared__ float redv[256];
  __shared__ int redi[256];
  __shared__ int bidxs[32];
  __shared__ double lred[8];

  const int tid = threadIdx.x;
  const int wid = tid >> 6;
  const int lane = tid & 63;
  const int rowbase = blockIdx.x * 32;

  // stage fp32 x rows
  {
    const float4* src = (const float4*)(x + (size_t)rowbase * D_DIM);
#pragma unroll
    for (int p = 0; p < 4; ++p) {
      int idx = p * 256 + tid;            // float4 index over 32x128
      int r = idx >> 5, c = idx & 31;
      *(float4*)(xf + r * 132 + c * 4) = src[idx];
    }
  }
  __syncthreads();

  // 8 lanes per row; per-candidate fp32 chain identical to validated version;
  // lexicographic (s, index) min is order-independent.
  {
    int gr = tid >> 3, sub = tid & 7;
    int c = (int)cnt_g[rowbase + gr];
    if (c <= CAP) {
      float xs2 = x2g[rowbase + gr];
      const float* xr = xf + gr * 132;
      float best = 3.4e38f;
      int bidx = 0x7fffffff;
      const unsigned short* lrow = lists_g + (size_t)(rowbase + gr) * CAP;
      for (int j = sub; j < c; j += 8) {
        int col = lrow[j];
        float dot = 0.f;
        const float4* ev = (const float4*)(emb + (size_t)col * D_DIM);
#pragma unroll 8
        for (int d4 = 0; d4 < 32; ++d4) {  // exact ascending-d fmaf chain
          float4 e4 = ev[d4];
          dot = __builtin_fmaf(xr[d4 * 4 + 0], e4.x, dot);
          dot = __builtin_fmaf(xr[d4 * 4 + 1], e4.y, dot);
          dot = __builtin_fmaf(xr[d4 * 4 + 2], e4.z, dot);
          dot = __builtin_fmaf(xr[d4 * 4 + 3], e4.w, dot);
        }
        float t1 = xs2 + e2g[col];                 // fl(x2+e2)
        float s = __builtin_fmaf(-2.0f, dot, t1);  // fl(t1 - 2*dot)
        if (s < best || (s == best && col < bidx)) { best = s; bidx = col; }
      }
#pragma unroll
      for (int off = 1; off <= 4; off <<= 1) {
        float ov = __shfl_xor(best, off, 64);
        int oi = __shfl_xor(bidx, off, 64);
        if (ov < best || (ov == best && oi < bidx)) { best = ov; bidx = oi; }
      }
      if (sub == 0) {
        out_idx[rowbase + gr] = (float)bidx;
        bidxs[gr] = bidx;
        atomicAdd(&counts[bidx], 1u);
      }
    }
  }
  __syncthreads();

  // overflow fallback: exact full scan (rare); cnt block-uniform per row
  for (int r = 0; r < 32; ++r) {
    if (cnt_g[rowbase + r] <= CAP) continue;
    float xs2 = x2g[rowbase + r];
    const float* xr = xf + r * 132;
    float lbest = 3.4e38f;
    int lidx = 0x7fffffff;
    for (int c0 = tid; c0 < K_CODES; c0 += 256) {
      float dot = 0.f;
      const float4* ev = (const float4*)(emb + (size_t)c0 * D_DIM);
      for (int d4 = 0; d4 < 32; ++d4) {
        float4 e4 = ev[d4];
        dot = __builtin_fmaf(xr[d4 * 4 + 0], e4.x, dot);
        dot = __builtin_fmaf(xr[d4 * 4 + 1], e4.y, dot);
        dot = __builtin_fmaf(xr[d4 * 4 + 2], e4.z, dot);
        dot = __builtin_fmaf(xr[d4 * 4 + 3], e4.w, dot);
      }
      float s = __builtin_fmaf(-2.0f, dot, xs2 + e2g[c0]);
      if (s < lbest || (s == lbest && c0 < lidx)) { lbest = s; lidx = c0; }
    }
    redv[tid] = lbest;
    redi[tid] = lidx;
    __syncthreads();
    if (tid == 0) {
      float bv = redv[0]; int bi = redi[0];
      for (int t = 1; t < 256; ++t) {
        float v = redv[t]; int i2 = redi[t];
        if (v < bv || (v == bv && i2 < bi)) { bv = v; bi = i2; }
      }
      out_idx[rowbase + r] = (float)bi;
      bidxs[r] = bi;
      atomicAdd(&counts[bi], 1u);
    }
    __syncthreads();
  }
  __syncthreads();  // bidxs ready for all rows

  // ---------------- fused gather + straight-through + losses ----------------
  {
    int gr = tid >> 3, seg = tid & 7;   // 8 threads/row, 16 floats each
    int gidx = bidxs[gr];
    const float4* ev = (const float4*)(emb + (size_t)gidx * D_DIM + seg * 16);
    const float* xvp = xf + gr * 132 + seg * 16;
    float4* oq = (float4*)(out_q + (size_t)(rowbase + gr) * D_DIM + seg * 16);
    double es = 0.0, qs = 0.0;
#pragma unroll
    for (int j = 0; j < 4; ++j) {
      float4 e4 = ev[j];
      float4 xv = *(const float4*)(xvp + j * 4);
      float d0 = e4.x - xv.x, d1 = e4.y - xv.y, d2 = e4.z - xv.z, d3 = e4.w - xv.w;
      float s0 = xv.x + d0, s1 = xv.y + d1, s2 = xv.z + d2, s3 = xv.w + d3;
      oq[j] = make_float4(s0, s1, s2, s3);
      float g0 = s0 - xv.x, g1 = s1 - xv.y, g2 = s2 - xv.z, g3 = s3 - xv.w;
      es += (double)(d0 * d0) + (double)(d1 * d1) + (double)(d2 * d2) + (double)(d3 * d3);
      qs += (double)(g0 * g0) + (double)(g1 * g1) + (double)(g2 * g2) + (double)(g3 * g3);
    }
#pragma unroll
    for (int off = 32; off >= 1; off >>= 1) {
      es += __shfl_down(es, off, 64);
      qs += __shfl_down(qs, off, 64);
    }
    if (lane == 0) { lred[wid * 2] = es; lred[wid * 2 + 1] = qs; }
    __syncthreads();
    if (tid == 0) {
      double e = lred[0] + lred[2] + lred[4] + lred[6];
      double qq = lred[1] + lred[3] + lred[5] + lred[7];
      atomicAdd(&sums[0], e);
      atomicAdd(&sums[1], qq);
    }
  }
}

// ---------------------------------------------------------------------------
// Kernel 3 (validated): finalize scalars.
// ---------------------------------------------------------------------------
__global__ __launch_bounds__(256) void vq_final(const unsigned int* __restrict__ counts,
                                                const double* __restrict__ sums,
                                                float* __restrict__ out_scalars) {
  double s = 0.0;
  for (int k = threadIdx.x; k < K_CODES; k += 256) {
    float p = (float)counts[k] * (1.0f / 32768.0f);
    float term = p * logf(p + 1e-10f);
    s += (double)term;
  }
#pragma unroll
  for (int off = 32; off >= 1; off >>= 1) s += __shfl_down(s, off, 64);
  __shared__ double red[4];
  if ((threadIdx.x & 63) == 0) red[threadIdx.x >> 6] = s;
  __syncthreads();
  if (threadIdx.x == 0) {
    double tot = red[0] + red[1] + red[2] + red[3];
    float e_lat = (float)(sums[0] / (double)(B_ROWS * D_DIM));
    float q_lat = (float)(sums[1] / (double)(B_ROWS * D_DIM));
    float vq = q_lat + 0.25f * e_lat;   // fl(q + fl(0.25*e)); 0.25*e exact
    out_scalars[0] = vq;
    out_scalars[1] = e_lat;
    out_scalars[2] = q_lat;
    out_scalars[3] = expf(-(float)tot);
  }
}

extern "C" void kernel_launch(void* const* d_in, const int* in_sizes, int n_in,
                              void* d_out, int out_size, void* d_ws, size_t ws_size,
                              hipStream_t stream) {
  const float* x = (const float*)d_in[0];
  const float* emb = (const float*)d_in[1];
  float* out = (float*)d_out;

  // ws: counts[4096]u32 @0 | sums[2]f64 @16384 | x2[32768] @16400 |
  //     e2[4096] @147472 | eb[4096*128]u16 @163856 |
  //     lists_g[32768*CAP]u16 @1212432 | cnt_g[32768]u32 @3309584  (~3.44 MB)
  unsigned int* counts = (unsigned int*)d_ws;
  double* sums = (double*)((char*)d_ws + 16384);
  float* x2 = (float*)((char*)d_ws + 16400);
  float* e2 = (float*)((char*)d_ws + 147472);
  unsigned short* eb = (unsigned short*)((char*)d_ws + 163856);
  unsigned short* lists_g = (unsigned short*)((char*)d_ws + 1212432);
  unsigned int* cnt_g = (unsigned int*)((char*)d_ws + 3309584);

  float* out_idx = out + (size_t)B_ROWS * D_DIM;
  float* out_scalars = out_idx + B_ROWS;

  hipMemsetAsync(d_ws, 0, 16400, stream);  // zero counts + sums
  prep<<<512, 256, 0, stream>>>(x, emb, x2, e2, eb);
  vq_scan<<<B_ROWS / 32, 256, 0, stream>>>(x, eb, e2, lists_g, cnt_g);
  vq_tail<<<B_ROWS / 32, 256, 0, stream>>>(x, emb, x2, e2, lists_g, cnt_g,
                                           out, out_idx, counts, sums);
  vq_final<<<1, 256, 0, stream>>>(counts, sums, out_scalars);
}